// Round 5
// baseline (428.430 us; speedup 1.0000x reference)
//
#include <hip/hip_runtime.h>

// VQ argmin, bit-replicating numpy fp32 reference (see R2).
// R5: R4's 8x8 tile + register-prefetch double-buffer so the vmcnt drain at
// each barrier lands AFTER the 4096-cyc FMA phase (latency hidden).
// Numerics identical to R4 (fmaf chain ascending k; fold fsub(fadd,fmul);
// pairwise norms). Split-K=4, merge/gather kernel.
// B=16 D=256 H=W=32 -> n=16384 pixels; K=2048 codes.

#define D_    256
#define K_    2048
#define HW_   1024
#define MT    64      // pixels per block (vq_k)
#define NT    256     // codes per LDS chunk
#define KT    32      // dims per k-chunk
#define SPLIT 4
#define KS    (K_ / SPLIT)   // 512 codes per block
#define CST   258     // cs row stride: even align, 2-way banks only (free)
#define NPIX  16384

// numpy pairwise combine of 8 accumulators
__device__ __forceinline__ float pw8(const float r[8]) {
    float t01 = __fadd_rn(r[0], r[1]);
    float t23 = __fadd_rn(r[2], r[3]);
    float L   = __fadd_rn(t01, t23);
    float t45 = __fadd_rn(r[4], r[5]);
    float t67 = __fadd_rn(r[6], r[7]);
    float R   = __fadd_rn(t45, t67);
    return __fadd_rn(L, R);
}

// norms: blocks [0,8) -> Bn (codebook rows); [8,264) -> An (64 pixels each)
__global__ __launch_bounds__(256) void norms_k(const float* __restrict__ z,
                                               const float* __restrict__ cb,
                                               float* __restrict__ An,
                                               float* __restrict__ Bn) {
    __shared__ float ls[D_ * 64];                  // 64 KB ([dim][pixel])
    int tid = threadIdx.x;
    if (blockIdx.x < 8) {
        int row = blockIdx.x * 256 + tid;
        const float4* p = reinterpret_cast<const float4*>(cb + (size_t)row * D_);
        float rA[8], rB[8];
        #pragma unroll
        for (int j = 0; j < 8; ++j) { rA[j] = 0.f; rB[j] = 0.f; }
        #pragma unroll
        for (int q = 0; q < 64; ++q) {
            float4 v = p[q];
            float pv[4] = {__fmul_rn(v.x, v.x), __fmul_rn(v.y, v.y),
                           __fmul_rn(v.z, v.z), __fmul_rn(v.w, v.w)};
            if (q < 32) {
                #pragma unroll
                for (int l = 0; l < 4; ++l)
                    rA[(4 * q + l) & 7] = __fadd_rn(rA[(4 * q + l) & 7], pv[l]);
            } else {
                #pragma unroll
                for (int l = 0; l < 4; ++l)
                    rB[(4 * q + l) & 7] = __fadd_rn(rB[(4 * q + l) & 7], pv[l]);
            }
        }
        Bn[row] = __fadd_rn(pw8(rA), pw8(rB));
    } else {
        int blk    = blockIdx.x - 8;               // [0,256)
        int b      = blk >> 4;
        int hwbase = (blk & 15) << 6;              // 64 pixels
        const float* zb = z + (size_t)b * (D_ * HW_) + hwbase;
        #pragma unroll
        for (int it = 0; it < 16; ++it) {          // stage 256 dims x 64 pix
            int u  = (it << 8) + tid;
            int dd = u >> 4;
            int m4 = u & 15;
            float4 v = *reinterpret_cast<const float4*>(
                zb + (size_t)dd * HW_ + (m4 << 2));
            *reinterpret_cast<float4*>(&ls[dd * 64 + (m4 << 2)]) = v;
        }
        __syncthreads();
        if (tid < 64) {
            float rA[8], rB[8];
            #pragma unroll
            for (int j = 0; j < 8; ++j) { rA[j] = 0.f; rB[j] = 0.f; }
            for (int d = 0; d < 128; ++d) {        // ascending d, exact chain
                float v = ls[d * 64 + tid];
                rA[d & 7] = __fadd_rn(rA[d & 7], __fmul_rn(v, v));
            }
            for (int d = 128; d < 256; ++d) {
                float v = ls[d * 64 + tid];
                rB[d & 7] = __fadd_rn(rB[d & 7], __fmul_rn(v, v));
            }
            An[(size_t)b * HW_ + hwbase + tid] = __fadd_rn(pw8(rA), pw8(rB));
        }
    }
}

// main GEMM+argmin over a K/SPLIT slice, register-prefetch double-buffered
__global__ __launch_bounds__(256, 2) void vq_k(const float* __restrict__ z,
                                               const float* __restrict__ cb,
                                               const float* __restrict__ An,
                                               const float* __restrict__ Bn,
                                               float* __restrict__ pscore,
                                               int* __restrict__ pidx) {
    __shared__ float smem[KT * MT + KT * CST];   // zs | cs ; aliased for reduce
    float* zs = smem;                 // [KT][MT]
    float* cs = smem + KT * MT;       // [KT][CST]
    float* rs = smem;                 // [MT][33] (aliased after barrier)
    int*   ri = (int*)(smem + MT * 33);

    const int tid = threadIdx.x;
    const int wv  = tid >> 6;
    const int tn  = (tid & 7) | (wv << 3);       // [0,32) n-group
    const int tm  = (tid >> 3) & 7;              // [0,8)  m-group
    const int blk = blockIdx.x;
    const int p   = blk >> 2;                    // pixel-block [0,256)
    const int s   = blk & 3;                     // K-split slice
    const int b      = p >> 4;
    const int hwbase = (p & 15) << 6;
    const float* zbase = z + (size_t)b * (D_ * HW_) + hwbase;
    const float* cbS   = cb + (size_t)s * KS * D_;

    // per-thread staging bases
    const float* zt = zbase + (size_t)(tid >> 4) * HW_ + ((tid & 15) << 2);
    const float* ct = cbS + (size_t)(tid >> 3) * D_ + ((tid & 7) << 2);
    const int zoff = (tid >> 4) * MT + ((tid & 15) << 2);
    const int nn0  = tid >> 3;
    const int db   = (tid & 7) << 2;

    float4 pz0, pz1, pc[8];
    #define LOADPH(ph)                                                        \
        do {                                                                  \
            const float* zp = zt + (size_t)((ph) & 7) * (KT * HW_);           \
            pz0 = *reinterpret_cast<const float4*>(zp);                       \
            pz1 = *reinterpret_cast<const float4*>(zp + 16 * HW_);            \
            const float* cp = ct + (size_t)((ph) >> 3) * (NT * D_)            \
                                 + (size_t)((ph) & 7) * KT;                   \
            _Pragma("unroll")                                                 \
            for (int it = 0; it < 8; ++it)                                    \
                pc[it] = *reinterpret_cast<const float4*>(cp + it * 32 * D_); \
        } while (0)

    float bs[8]; int bi[8];
    #pragma unroll
    for (int i = 0; i < 8; ++i) { bs[i] = 1e30f; bi[i] = 0; }

    LOADPH(0);

    for (int nc = 0; nc < 2; ++nc) {
        float acc[8][8];
        #pragma unroll
        for (int i = 0; i < 8; ++i)
            #pragma unroll
            for (int j = 0; j < 8; ++j) acc[i][j] = 0.f;

        for (int kc = 0; kc < 8; ++kc) {
            const int ph = nc * 8 + kc;
            __syncthreads();               // prev compute done with LDS
            {   // store prefetched tile (vmcnt drain was hidden by prev compute)
                *reinterpret_cast<float4*>(&zs[zoff]) = pz0;
                *reinterpret_cast<float4*>(&zs[zoff + 16 * MT]) = pz1;
                #pragma unroll
                for (int it = 0; it < 8; ++it) {
                    int nn = (it << 5) + nn0;
                    cs[(db + 0) * CST + nn] = pc[it].x;
                    cs[(db + 1) * CST + nn] = pc[it].y;
                    cs[(db + 2) * CST + nn] = pc[it].z;
                    cs[(db + 3) * CST + nn] = pc[it].w;
                }
            }
            __syncthreads();               // tile visible
            if (ph < 15) {                 // issue next phase's loads async
                LOADPH(ph + 1);
            }
            // ascending-k single-acc FMA chain — bit-matches sgemm
            #pragma unroll
            for (int d = 0; d < KT; ++d) {
                const float* zr = &zs[d * MT + (tm << 3)];
                float4 a0 = *reinterpret_cast<const float4*>(zr);
                float4 a1 = *reinterpret_cast<const float4*>(zr + 4);
                const float* crow = &cs[d * CST + (tn << 3)];
                float4 b0 = *reinterpret_cast<const float4*>(crow);
                float4 b1 = *reinterpret_cast<const float4*>(crow + 4);
                float av[8] = {a0.x, a0.y, a0.z, a0.w, a1.x, a1.y, a1.z, a1.w};
                float bv[8] = {b0.x, b0.y, b0.z, b0.w, b1.x, b1.y, b1.z, b1.w};
                #pragma unroll
                for (int i = 0; i < 8; ++i)
                    #pragma unroll
                    for (int j = 0; j < 8; ++j)
                        acc[i][j] = fmaf(av[i], bv[j], acc[i][j]);
            }
        }
        // fold: d = fp32( fp32(A+B) - 2*M ), ascending code index
        #pragma unroll
        for (int j = 0; j < 8; ++j) {
            int nl = (tn << 3) + j;
            int ng = s * KS + nc * NT + nl;
            float bn = Bn[ng];
            #pragma unroll
            for (int i = 0; i < 8; ++i) {
                float an = An[(size_t)b * HW_ + hwbase + (tm << 3) + i];
                float sc = __fsub_rn(__fadd_rn(an, bn),
                                     __fmul_rn(2.0f, acc[i][j]));
                if (sc < bs[i]) { bs[i] = sc; bi[i] = ng; }
            }
        }
    }
    #undef LOADPH

    __syncthreads();   // protect smem before aliasing
    #pragma unroll
    for (int i = 0; i < 8; ++i) {
        int m = (tm << 3) + i;
        rs[m * 33 + tn] = bs[i];
        ri[m * 33 + tn] = bi[i];
    }
    __syncthreads();
    if (tid < MT) {
        int   m    = tid;
        float best = rs[m * 33];
        int   bidx = ri[m * 33];
        for (int t = 1; t < 32; ++t) {
            float sv = rs[m * 33 + t];
            int   ix = ri[m * 33 + t];
            if (sv < best || (sv == best && ix < bidx)) { best = sv; bidx = ix; }
        }
        int g = b * HW_ + hwbase + m;
        pscore[s * NPIX + g] = best;
        pidx[s * NPIX + g]   = bidx;
    }
}

// merge SPLIT partials (first-min tiebreak) + gather output
__global__ __launch_bounds__(256) void fin_k(const float* __restrict__ cb,
                                             const float* __restrict__ pscore,
                                             const int* __restrict__ pidx,
                                             float* __restrict__ out) {
    __shared__ int idxs[MT];
    int tid = threadIdx.x;
    int p   = blockIdx.x;               // [0,256)
    int b      = p >> 4;
    int hwbase = (p & 15) << 6;
    if (tid < MT) {
        int g = b * HW_ + hwbase + tid;
        float best = pscore[g];
        int   bidx = pidx[g];
        #pragma unroll
        for (int s = 1; s < SPLIT; ++s) {
            float sv = pscore[s * NPIX + g];
            int   ix = pidx[s * NPIX + g];
            if (sv < best || (sv == best && ix < bidx)) { best = sv; bidx = ix; }
        }
        idxs[tid] = bidx;
    }
    __syncthreads();
    float* obase = out + (size_t)b * (D_ * HW_) + hwbase;
    #pragma unroll
    for (int it = 0; it < 16; ++it) {
        int u  = (it << 8) + tid;
        int dd = u >> 4;                // [0,256)
        int m4 = u & 15;
        int i0 = idxs[(m4 << 2) + 0];
        int i1 = idxs[(m4 << 2) + 1];
        int i2 = idxs[(m4 << 2) + 2];
        int i3 = idxs[(m4 << 2) + 3];
        float4 o;
        o.x = cb[(size_t)i0 * D_ + dd];
        o.y = cb[(size_t)i1 * D_ + dd];
        o.z = cb[(size_t)i2 * D_ + dd];
        o.w = cb[(size_t)i3 * D_ + dd];
        *reinterpret_cast<float4*>(obase + (size_t)dd * HW_ + (m4 << 2)) = o;
    }
}

extern "C" void kernel_launch(void* const* d_in, const int* in_sizes, int n_in,
                              void* d_out, int out_size, void* d_ws, size_t ws_size,
                              hipStream_t stream) {
    const float* z  = (const float*)d_in[0];   // 16*256*32*32
    const float* cb = (const float*)d_in[1];   // 2048*256
    float* An     = (float*)d_ws;                       // 16384
    float* Bn     = An + NPIX;                          // 2048
    float* pscore = Bn + K_;                            // 4*16384
    int*   pidx   = (int*)(pscore + SPLIT * NPIX);      // 4*16384
    float* out    = (float*)d_out;

    norms_k<<<dim3(264), dim3(256), 0, stream>>>(z, cb, An, Bn);
    vq_k<<<dim3(256 * SPLIT), dim3(256), 0, stream>>>(z, cb, An, Bn, pscore, pidx);
    fin_k<<<dim3(256), dim3(256), 0, stream>>>(cb, pscore, pidx, out);
}

// Round 6
// 293.957 us; speedup vs baseline: 1.4575x; 1.4575x over previous
//
#include <hip/hip_runtime.h>
#include <stdint.h>

// VQ argmin, bit-replicating numpy fp32 reference (see R2).
// R6: pre-transposed codebook + global_load_lds(16B) staging (zero staging
// VGPRs -> no spill) + true LDS double-buffer (barrier -> issue next-phase
// DMA -> 2048cyc FMA hides the vmcnt drain). KT=16, SPLIT=2 (grid 512 = 2
// blocks/CU exactly). Numerics identical to R2-R5 (ascending-k fmaf chain).
// B=16 D=256 H=W=32 -> n=16384 pixels; K=2048 codes.

#define D_    256
#define K_    2048
#define HW_   1024
#define MT    64      // pixels per block
#define NT    256     // codes per acc chunk
#define KT    16      // dims per phase
#define SPLIT 2
#define KS    (K_ / SPLIT)   // 1024 codes per block
#define CST   260     // cs row stride: 16B-aligned rows, 2-way banks (free)
#define BUFSZ (KT * MT + KT * CST)   // 5184 floats per buffer
#define NPIX  16384

// global -> LDS direct DMA, 16 B per lane, wave-uniform LDS base (CK-style casts)
__device__ __forceinline__ void gload16(const float* g, float* l) {
    auto* gp = reinterpret_cast<const __attribute__((address_space(1))) uint32_t*>(
        reinterpret_cast<uintptr_t>(g));
    auto* lp = reinterpret_cast<__attribute__((address_space(3))) uint32_t*>(
        reinterpret_cast<uintptr_t>(l));
    __builtin_amdgcn_global_load_lds(gp, lp, 16, 0, 0);
}

// numpy pairwise combine of 8 accumulators
__device__ __forceinline__ float pw8(const float r[8]) {
    float t01 = __fadd_rn(r[0], r[1]);
    float t23 = __fadd_rn(r[2], r[3]);
    float L   = __fadd_rn(t01, t23);
    float t45 = __fadd_rn(r[4], r[5]);
    float t67 = __fadd_rn(r[6], r[7]);
    float R   = __fadd_rn(t45, t67);
    return __fadd_rn(L, R);
}

// prep: blocks [0,128) transpose cb->ct; [128,136) Bn; [136,200) An
__global__ __launch_bounds__(256) void prep_k(const float* __restrict__ z,
                                              const float* __restrict__ cb,
                                              float* __restrict__ ct,
                                              float* __restrict__ An,
                                              float* __restrict__ Bn) {
    __shared__ float t[64][65];
    int tid = threadIdx.x;
    int bx  = blockIdx.x;
    if (bx < 128) {
        int k0 = (bx & 31) << 6;
        int d0 = (bx >> 5) << 6;
        #pragma unroll
        for (int it = 0; it < 4; ++it) {
            int u  = (it << 8) + tid;
            int kk = u >> 4;
            int dd = (u & 15) << 2;
            float4 v = *reinterpret_cast<const float4*>(
                cb + (size_t)(k0 + kk) * D_ + d0 + dd);
            t[kk][dd + 0] = v.x; t[kk][dd + 1] = v.y;
            t[kk][dd + 2] = v.z; t[kk][dd + 3] = v.w;
        }
        __syncthreads();
        #pragma unroll
        for (int it = 0; it < 4; ++it) {
            int u  = (it << 8) + tid;
            int dd = u >> 4;
            int kk = (u & 15) << 2;
            float4 o;
            o.x = t[kk + 0][dd]; o.y = t[kk + 1][dd];
            o.z = t[kk + 2][dd]; o.w = t[kk + 3][dd];
            *reinterpret_cast<float4*>(ct + (size_t)(d0 + dd) * K_ + k0 + kk) = o;
        }
    } else if (bx < 136) {
        int row = (bx - 128) * 256 + tid;
        const float4* p = reinterpret_cast<const float4*>(cb + (size_t)row * D_);
        float rA[8], rB[8];
        #pragma unroll
        for (int j = 0; j < 8; ++j) { rA[j] = 0.f; rB[j] = 0.f; }
        #pragma unroll
        for (int q = 0; q < 64; ++q) {
            float4 v = p[q];
            float pv[4] = {__fmul_rn(v.x, v.x), __fmul_rn(v.y, v.y),
                           __fmul_rn(v.z, v.z), __fmul_rn(v.w, v.w)};
            if (q < 32) {
                #pragma unroll
                for (int l = 0; l < 4; ++l)
                    rA[(4 * q + l) & 7] = __fadd_rn(rA[(4 * q + l) & 7], pv[l]);
            } else {
                #pragma unroll
                for (int l = 0; l < 4; ++l)
                    rB[(4 * q + l) & 7] = __fadd_rn(rB[(4 * q + l) & 7], pv[l]);
            }
        }
        Bn[row] = __fadd_rn(pw8(rA), pw8(rB));
    } else {
        int blk = bx - 136;                  // [0,64): 256 pixels each
        int b   = blk >> 2;
        int hw0 = (blk & 3) << 8;
        const float* zb = z + (size_t)b * (D_ * HW_) + hw0 + tid;
        float rA[8], rB[8];
        #pragma unroll
        for (int j = 0; j < 8; ++j) { rA[j] = 0.f; rB[j] = 0.f; }
        #pragma unroll 8
        for (int d = 0; d < 128; ++d) {      // coalesced: consecutive threads
            float v = zb[(size_t)d * HW_];
            rA[d & 7] = __fadd_rn(rA[d & 7], __fmul_rn(v, v));
        }
        #pragma unroll 8
        for (int d = 128; d < 256; ++d) {
            float v = zb[(size_t)d * HW_];
            rB[d & 7] = __fadd_rn(rB[d & 7], __fmul_rn(v, v));
        }
        An[(size_t)b * HW_ + hw0 + tid] = __fadd_rn(pw8(rA), pw8(rB));
    }
}

// main GEMM+argmin: LDS double-buffered via global_load_lds DMA
__global__ __launch_bounds__(256, 2) void vq_k(const float* __restrict__ z,
                                               const float* __restrict__ ct,
                                               const float* __restrict__ An,
                                               const float* __restrict__ Bn,
                                               float* __restrict__ pscore,
                                               int* __restrict__ pidx) {
    __shared__ float smem[2 * BUFSZ];            // 41472 B
    float* rs = smem;                            // aliased for reduce
    int*   ri = (int*)(smem + MT * 33);

    const int tid  = threadIdx.x;
    const int lane = tid & 63;
    const int w    = tid >> 6;                   // wave id [0,4)
    const int tn   = (tid & 7) | (w << 3);       // [0,32) code-group
    const int tm   = (tid >> 3) & 7;             // [0,8)  pixel-group
    const int blk  = blockIdx.x;
    const int p    = blk >> 1;                   // pixel-block [0,256)
    const int s    = blk & 1;                    // K-split slice
    const int b      = p >> 4;
    const int hwbase = (p & 15) << 6;
    const float* zbase = z + (size_t)b * (D_ * HW_) + hwbase;
    const float* ctS   = ct + s * KS;

    // per-lane DMA source bases (z: lane covers row 4w+(lane>>4), col (lane&15)*4)
    const float* zsrc = zbase + (size_t)((w << 2) + (lane >> 4)) * HW_
                              + ((lane & 15) << 2);

    float bs[8]; int bi[8];
    #pragma unroll
    for (int i = 0; i < 8; ++i) { bs[i] = 1e30f; bi[i] = 0; }
    float acc[8][8];
    #pragma unroll
    for (int i = 0; i < 8; ++i)
        #pragma unroll
        for (int j = 0; j < 8; ++j) acc[i][j] = 0.f;

    // stage phase ph into buf[ph&1]: 1 z-DMA + 4 cs-row-DMAs per wave
    #define STAGE(ph)                                                         \
        do {                                                                  \
            int buf_ = (ph) & 1, kc_ = (ph) & 15, nc_ = (ph) >> 4;            \
            float* zb_ = smem + buf_ * BUFSZ;                                 \
            float* cb_ = zb_ + KT * MT;                                       \
            gload16(zsrc + (size_t)kc_ * (KT * HW_), zb_ + (w << 2) * MT);    \
            _Pragma("unroll")                                                 \
            for (int r = 0; r < 4; ++r) {                                     \
                int row = (w << 2) + r;                                       \
                gload16(ctS + (size_t)((kc_ << 4) + row) * K_ + nc_ * NT      \
                            + (lane << 2),                                    \
                        cb_ + row * CST);                                     \
            }                                                                 \
        } while (0)

    STAGE(0);

    for (int ph = 0; ph < 64; ++ph) {
        __syncthreads();          // drains phase-ph DMA (issued 1 phase ago)
        if (ph < 63) STAGE(ph + 1);   // into other buffer (safe: read at ph-1)
        const float* zb_ = smem + (ph & 1) * BUFSZ;
        const float* cb_ = zb_ + KT * MT;
        // ascending-k single-acc FMA chain — bit-matches sgemm
        #pragma unroll
        for (int d = 0; d < KT; ++d) {
            const float* zr = zb_ + d * MT + (tm << 3);
            float4 a0 = *reinterpret_cast<const float4*>(zr);
            float4 a1 = *reinterpret_cast<const float4*>(zr + 4);
            const float* cr = cb_ + d * CST + (tn << 3);
            float4 b0 = *reinterpret_cast<const float4*>(cr);
            float4 b1 = *reinterpret_cast<const float4*>(cr + 4);
            float av[8] = {a0.x, a0.y, a0.z, a0.w, a1.x, a1.y, a1.z, a1.w};
            float bv[8] = {b0.x, b0.y, b0.z, b0.w, b1.x, b1.y, b1.z, b1.w};
            #pragma unroll
            for (int i = 0; i < 8; ++i)
                #pragma unroll
                for (int j = 0; j < 8; ++j)
                    acc[i][j] = fmaf(av[i], bv[j], acc[i][j]);
        }
        if ((ph & 15) == 15) {
            int nc = ph >> 4;
            #pragma unroll
            for (int j = 0; j < 8; ++j) {
                int ng = s * KS + nc * NT + (tn << 3) + j;
                float bn = Bn[ng];
                #pragma unroll
                for (int i = 0; i < 8; ++i) {
                    float an = An[(size_t)b * HW_ + hwbase + (tm << 3) + i];
                    float sc = __fsub_rn(__fadd_rn(an, bn),
                                         __fmul_rn(2.0f, acc[i][j]));
                    if (sc < bs[i]) { bs[i] = sc; bi[i] = ng; }
                }
            }
            #pragma unroll
            for (int i = 0; i < 8; ++i)
                #pragma unroll
                for (int j = 0; j < 8; ++j) acc[i][j] = 0.f;
        }
    }
    #undef STAGE

    __syncthreads();   // protect smem before aliasing
    #pragma unroll
    for (int i = 0; i < 8; ++i) {
        int m = (tm << 3) + i;
        rs[m * 33 + tn] = bs[i];
        ri[m * 33 + tn] = bi[i];
    }
    __syncthreads();
    if (tid < MT) {
        int   m    = tid;
        float best = rs[m * 33];
        int   bidx = ri[m * 33];
        for (int t = 1; t < 32; ++t) {
            float sv = rs[m * 33 + t];
            int   ix = ri[m * 33 + t];
            if (sv < best || (sv == best && ix < bidx)) { best = sv; bidx = ix; }
        }
        int g = b * HW_ + hwbase + m;
        pscore[s * NPIX + g] = best;
        pidx[s * NPIX + g]   = bidx;
    }
}

// merge SPLIT partials (first-min tiebreak) + gather output
__global__ __launch_bounds__(256) void fin_k(const float* __restrict__ cb,
                                             const float* __restrict__ pscore,
                                             const int* __restrict__ pidx,
                                             float* __restrict__ out) {
    __shared__ int idxs[MT];
    int tid = threadIdx.x;
    int p   = blockIdx.x;               // [0,256)
    int b      = p >> 4;
    int hwbase = (p & 15) << 6;
    if (tid < MT) {
        int g = b * HW_ + hwbase + tid;
        float best = pscore[g];
        int   bidx = pidx[g];
        #pragma unroll
        for (int s = 1; s < SPLIT; ++s) {
            float sv = pscore[s * NPIX + g];
            int   ix = pidx[s * NPIX + g];
            if (sv < best || (sv == best && ix < bidx)) { best = sv; bidx = ix; }
        }
        idxs[tid] = bidx;
    }
    __syncthreads();
    float* obase = out + (size_t)b * (D_ * HW_) + hwbase;
    #pragma unroll
    for (int it = 0; it < 16; ++it) {
        int u  = (it << 8) + tid;
        int dd = u >> 4;                // [0,256)
        int m4 = u & 15;
        int i0 = idxs[(m4 << 2) + 0];
        int i1 = idxs[(m4 << 2) + 1];
        int i2 = idxs[(m4 << 2) + 2];
        int i3 = idxs[(m4 << 2) + 3];
        float4 o;
        o.x = cb[(size_t)i0 * D_ + dd];
        o.y = cb[(size_t)i1 * D_ + dd];
        o.z = cb[(size_t)i2 * D_ + dd];
        o.w = cb[(size_t)i3 * D_ + dd];
        *reinterpret_cast<float4*>(obase + (size_t)dd * HW_ + (m4 << 2)) = o;
    }
}

extern "C" void kernel_launch(void* const* d_in, const int* in_sizes, int n_in,
                              void* d_out, int out_size, void* d_ws, size_t ws_size,
                              hipStream_t stream) {
    const float* z  = (const float*)d_in[0];   // 16*256*32*32
    const float* cb = (const float*)d_in[1];   // 2048*256
    float* pscore = (float*)d_ws;                       // 2*16384
    int*   pidx   = (int*)(pscore + SPLIT * NPIX);      // 2*16384
    float* An     = (float*)(pidx + SPLIT * NPIX);      // 16384
    float* Bn     = An + NPIX;                          // 2048
    float* ct     = Bn + K_;                            // 256*2048 (2 MB)
    float* out    = (float*)d_out;

    prep_k<<<dim3(200), dim3(256), 0, stream>>>(z, cb, ct, An, Bn);
    vq_k<<<dim3(256 * SPLIT), dim3(256), 0, stream>>>(z, ct, An, Bn, pscore, pidx);
    fin_k<<<dim3(256), dim3(256), 0, stream>>>(cb, pscore, pidx, out);
}